// Round 9
// baseline (1963.210 us; speedup 1.0000x reference)
//
#include <hip/hip_runtime.h>

#define TF 32000

typedef short s8v __attribute__((ext_vector_type(8)));
typedef float f4v __attribute__((ext_vector_type(4)));
typedef unsigned int ui4 __attribute__((ext_vector_type(4)));

// ---------- helpers ----------
__device__ __forceinline__ float us2f(unsigned int u16) {
  union { float f; unsigned int i; } v; v.i = u16 << 16; return v.f;
}
__device__ __forceinline__ unsigned short f2b(float f) {  // RNE float->bf16
  union { float f; unsigned int u; } v; v.f = f;
  unsigned int u = v.u;
  u = (u + 0x7fffu + ((u >> 16) & 1u)) >> 16;
  return (unsigned short)u;
}
// fast tanh(a)*sigmoid(g): 2x v_exp + v_rcp, ~1e-7 rel err
__device__ __forceinline__ float gatef(float a, float g) {
  a = fminf(fmaxf(a, -15.f), 15.f);
  float ta = __expf(2.f * a);
  float sg = __expf(-g);
  return (ta - 1.f) * __builtin_amdgcn_rcpf((ta + 1.f) * (1.f + sg));
}

// ---------- probe: x int64 vs int32 (bit0 = int32) ----------
__global__ void k_probe_x(const int* __restrict__ x, int* __restrict__ flag) {
  int acc = 0;
  for (int i = blockIdx.x * 256 + threadIdx.x; i < 64000; i += 32 * 256)
    acc |= x[2 * i + 1];
  unsigned long long m = __ballot(acc != 0);
  if ((threadIdx.x & 63) == 0 && m != 0ULL) atomicOr(flag, 1);
}

// ---------- probe: weights fp32 vs bf16 (bit1 = fp32) ----------
__global__ void k_probe_dt(const unsigned short* __restrict__ fw, int* __restrict__ flag) {
  int i = blockIdx.x * 256 + threadIdx.x;   // 64 blocks * 256 = 16384
  float v = us2f(fw[i]);
  int bad = !(fabsf(v) <= 1.0f);            // catches >1 and NaN
  unsigned long long m = __ballot(bad);
  if ((threadIdx.x & 63) == 0 && m != 0ULL) atomicOr(flag, 2);
}

// ---------- convert all params to canonical fp32 ----------
struct SrcPtrs { const void* p[17]; };

__global__ __launch_bounds__(256) void k_cvt(SrcPtrs sp, const int* __restrict__ flag,
                                             float* __restrict__ wdst, float* __restrict__ cdst) {
  int i = blockIdx.x * 256 + threadIdx.x;
  if (i >= 1223846) return;
  const bool f32 = ((*flag) & 2) != 0;
  int s, base;
  if (i < 507968) {
    if (i < 16384)       { s = 0;  base = 0; }
    else if (i < 16448)  { s = 1;  base = 16384; }
    else                 { s = 2;  base = 16448; }
  } else if (i < 943808) {
    if (i < 511808)      { s = 3;  base = 507968; }
    else if (i < 819008) { s = 4;  base = 511808; }
    else if (i < 941888) { s = 5;  base = 819008; }
    else                 { s = 6;  base = 941888; }
  } else if (i < 1089408) {
    if (i < 1066688)      { s = 7;  base = 943808; }
    else if (i < 1068608) { s = 8;  base = 1066688; }
    else if (i < 1072704) { s = 9;  base = 1068608; }
    else if (i < 1072768) { s = 10; base = 1072704; }
    else if (i < 1089152) { s = 11; base = 1072768; }
    else                  { s = 12; base = 1089152; }
  } else {
    if (i < 1095808)      { s = 13; base = 1089408; }
    else if (i < 1095829) { s = 14; base = 1095808; }
    else if (i < 1095846) { s = 15; base = 1095829; }
    else                  { s = 16; base = 1095846; }
  }
  int j = i - base;
  const void* src = sp.p[s];
  float v = f32 ? ((const float*)src)[j] : us2f(((const unsigned short*)src)[j]);
  if (s == 16) cdst[j] = v; else wdst[i] = v;
}

// ---------- pack layer weights into MFMA layout, split bf16 hi/lo ----------
__global__ __launch_bounds__(256) void k_pack(const float* __restrict__ wc,
    unsigned short* __restrict__ w1h, unsigned short* __restrict__ w1l,
    unsigned short* __restrict__ w2h, unsigned short* __restrict__ w2l) {
  int i = blockIdx.x * 256 + threadIdx.x;
  if (i < 860160) {
    int l = i / 28672, r = i % 28672, o = r / 224, k = r % 224;
    float v = 0.f;
    if (k < 128)      v = wc[16448 + l * 16384 + o * 128 + (k & 63) * 2 + (k >> 6)];
    else if (k < 208) v = wc[511808 + l * 10240 + o * 80 + (k - 128)];
    unsigned short hh = f2b(v);
    w1h[i] = hh;
    w1l[i] = f2b(v - us2f(hh));
  } else if (i < 1105920) {
    int j = i - 860160;
    int l = j / 8192, r = j % 8192, o = r / 64, ch = r % 64;
    float v = (o < 64) ? wc[819008 + l * 4096 + o * 64 + ch]
                       : wc[943808 + l * 4096 + (o - 64) * 64 + ch];
    unsigned short hh = f2b(v);
    w2h[j] = hh;
    w2l[j] = f2b(v - us2f(hh));
  }
}

// ---------- 1x1 conv_in ----------
__global__ void k_convin(const float* __restrict__ c, const float* __restrict__ w,
                         float* __restrict__ c0) {
  int b = blockIdx.x / 400, t = blockIdx.x % 400;
  int o = threadIdx.x;
  if (o >= 80) return;
  const float* crow = c + b * 80 * 400 + t;
  const float* wrow = w + o * 80;
  float acc = 0.f;
  for (int k = 0; k < 80; ++k) acc += wrow[k] * crow[k * 400];
  c0[(b * 80 + o) * 400 + t] = acc;
}

// ---------- upsample stage 1: repeat x10, k=21 'same' (fp32 out) ----------
__global__ void k_up1(const float* __restrict__ c0, const float* __restrict__ w,
                      float* __restrict__ s1) {
  int id = blockIdx.x * 256 + threadIdx.x;   // [0, 1,280,000)
  int t = id % 4000;
  int bc = id / 4000;
  const float* src = c0 + bc * 400;
  float acc = 0.f;
  #pragma unroll
  for (int j = 0; j < 21; ++j) {
    int tt = t - 10 + j;
    if (tt >= 0 && tt < 4000) acc += w[j] * src[tt / 10];
  }
  s1[id] = acc;
}

// ---------- upsample stage 2: repeat x8, k=17, channel-pair-packed bf16 out ----------
__global__ void k_up2(const float* __restrict__ s1, const float* __restrict__ w,
                      unsigned int* __restrict__ cpk) {
  int id = blockIdx.x * 256 + threadIdx.x;   // [0, 5,120,000)
  int t = id % TF;
  int cp = (id / TF) % 40;
  int b = id / (40 * TF);
  const float* src0 = s1 + (b * 80 + cp * 2) * 4000;
  const float* src1 = src0 + 4000;
  float a0 = 0.f, a1 = 0.f;
  #pragma unroll
  for (int j = 0; j < 17; ++j) {
    int tt = t - 8 + j;
    if (tt >= 0 && tt < TF) {
      int q = tt / 8;
      a0 += w[j] * src0[q];
      a1 += w[j] * src1[q];
    }
  }
  cpk[id] = (unsigned int)f2b(a0) | ((unsigned int)f2b(a1) << 16);
}

// ---------- first conv (embedding gather) -> pre-split packed h planes ----------
__global__ void k_first(const int* __restrict__ x, const int* __restrict__ flag,
                        const float* __restrict__ fw, const float* __restrict__ fb,
                        unsigned int* __restrict__ hhi, unsigned int* __restrict__ hlo) {
  int id = blockIdx.x * 256 + threadIdx.x;   // [0, 4,096,000)
  int t = id % TF;
  int rp = (id / TF) & 31;
  int b = id / (32 * TF);
  int i = b * TF + t;
  int idx = (((*flag) & 1) ? x[i] : x[2 * i]) & 255;
  int r0 = rp * 2;
  float v0 = fw[r0 * 256 + idx] + fb[r0];
  float v1 = fw[(r0 + 1) * 256 + idx] + fb[r0 + 1];
  unsigned int h0 = f2b(v0), h1 = f2b(v1);
  hhi[id] = h0 | (h1 << 16);
  hlo[id] = (unsigned int)f2b(v0 - us2f(h0)) | ((unsigned int)f2b(v1 - us2f(h1)) << 16);
}

// ---------- single WaveNet residual layer (unfused; R8-verified) ----------
__global__ __launch_bounds__(256, 4) void k_layer(
    const unsigned int* __restrict__ hhi_in, const unsigned int* __restrict__ hlo_in,
    unsigned int* __restrict__ hhi_out, unsigned int* __restrict__ hlo_out,
    float* __restrict__ skips, const unsigned int* __restrict__ cpk,
    const unsigned short* __restrict__ w1h, const unsigned short* __restrict__ w1l,
    const unsigned short* __restrict__ w2h, const unsigned short* __restrict__ w2l,
    const float* __restrict__ db, const float* __restrict__ sb,
    const float* __restrict__ ob, int d, int mode) {
  __shared__ __align__(16) unsigned char smem[34816];
  unsigned short (*Xhi)[136] = (unsigned short (*)[136])smem;
  unsigned short (*Xlo)[136] = (unsigned short (*)[136])(smem + 17408);
  unsigned short (*Zhi)[72]  = (unsigned short (*)[72])smem;
  unsigned short (*Zlo)[72]  = (unsigned short (*)[72])(smem + 9216);
  const int obid = (blockIdx.x & 7) * 250 + (blockIdx.x >> 3);
  const int b = obid / 500;
  const int t0 = (obid % 500) * 64;
  const int tid = threadIdx.x;
  const int wv = tid >> 6, l15 = tid & 15, kl = (tid >> 4) & 3;
  const int R0 = wv * 16, R1 = 64 + wv * 16;
  const int ko = kl * 8;
  const unsigned int* hhiB = hhi_in + (size_t)b * 32 * TF;
  const unsigned int* hloB = hlo_in + (size_t)b * 32 * TF;
  const unsigned int* cpkB = cpk + (size_t)b * 40 * TF;

  const int r0e = R0 + kl * 4;
  float* sp_ = skips + ((size_t)b * 64 + r0e) * TF + t0;
  float s_old[16];
  if (!(mode & 1)) {
    #pragma unroll
    for (int ct = 0; ct < 4; ++ct) {
      const int t = ct * 16 + l15;
      s_old[ct * 4 + 0] = sp_[0 * TF + t];
      s_old[ct * 4 + 1] = sp_[1 * TF + t];
      s_old[ct * 4 + 2] = sp_[2 * TF + t];
      s_old[ct * 4 + 3] = sp_[3 * TF + t];
    }
  } else {
    #pragma unroll
    for (int q = 0; q < 16; ++q) s_old[q] = 0.f;
  }

  const bool d4 = (d & 3) == 0;
  for (int u = tid; u < 1024; u += 256) {
    const int g = u & 63, blk = u >> 6;
    const int cp = (g & 7) | ((blk & 3) << 3);
    const int tq = (g >> 3) | ((blk & 4) << 1);
    const int arr = blk >> 3;
    const int row = cp * TF;
    ui4 hv, lv;
    if (arr == 0) {
      hv = *(const ui4*)(hhiB + row + t0 + tq * 4);
      lv = *(const ui4*)(hloB + row + t0 + tq * 4);
    } else {
      const int base = t0 - d + tq * 4;
      if (d4 && base >= 0) {
        hv = *(const ui4*)(hhiB + row + base);
        lv = *(const ui4*)(hloB + row + base);
      } else {
        #pragma unroll
        for (int q = 0; q < 4; ++q) {
          int tp = base + q;
          hv[q] = tp >= 0 ? hhiB[row + tp] : 0u;
          lv[q] = tp >= 0 ? hloB[row + tp] : 0u;
        }
      }
    }
    const int colb = (arr ? 0 : 64) + cp * 2;
    #pragma unroll
    for (int q = 0; q < 4; ++q) {
      const int t = tq * 4 + q;
      *(unsigned int*)&Xhi[t][colb] = hv[q];
      *(unsigned int*)&Xlo[t][colb] = lv[q];
    }
  }
  __syncthreads();

  f4v accA[4], accG[4];
  {
    f4v bA = *(const f4v*)(db + R0 + kl * 4);
    f4v bG = *(const f4v*)(db + R1 + kl * 4);
    #pragma unroll
    for (int ct = 0; ct < 4; ++ct) { accA[ct] = bA; accG[ct] = bG; }
  }
  #pragma unroll
  for (int s = 0; s < 4; ++s) {
    const int k0 = s * 32 + ko;
    s8v ah0 = *(const s8v*)(w1h + (R0 + l15) * 224 + k0);
    s8v ah1 = *(const s8v*)(w1h + (R1 + l15) * 224 + k0);
    s8v al0 = *(const s8v*)(w1l + (R0 + l15) * 224 + k0);
    s8v al1 = *(const s8v*)(w1l + (R1 + l15) * 224 + k0);
    #pragma unroll
    for (int ct = 0; ct < 4; ++ct) {
      s8v bh = *(const s8v*)&Xhi[ct * 16 + l15][k0];
      s8v bl = *(const s8v*)&Xlo[ct * 16 + l15][k0];
      accA[ct] = __builtin_amdgcn_mfma_f32_16x16x32_bf16(ah0, bh, accA[ct], 0, 0, 0);
      accG[ct] = __builtin_amdgcn_mfma_f32_16x16x32_bf16(ah1, bh, accG[ct], 0, 0, 0);
      accA[ct] = __builtin_amdgcn_mfma_f32_16x16x32_bf16(al0, bh, accA[ct], 0, 0, 0);
      accG[ct] = __builtin_amdgcn_mfma_f32_16x16x32_bf16(al1, bh, accG[ct], 0, 0, 0);
      accA[ct] = __builtin_amdgcn_mfma_f32_16x16x32_bf16(ah0, bl, accA[ct], 0, 0, 0);
      accG[ct] = __builtin_amdgcn_mfma_f32_16x16x32_bf16(ah1, bl, accG[ct], 0, 0, 0);
    }
  }
  #pragma unroll
  for (int s = 4; s < 7; ++s) {
    const int k0 = s * 32 + ko;
    s8v ah0 = *(const s8v*)(w1h + (R0 + l15) * 224 + k0);
    s8v ah1 = *(const s8v*)(w1h + (R1 + l15) * 224 + k0);
    s8v al0 = *(const s8v*)(w1l + (R0 + l15) * 224 + k0);
    s8v al1 = *(const s8v*)(w1l + (R1 + l15) * 224 + k0);
    const int cp0 = (k0 - 128) >> 1;
    #pragma unroll
    for (int ct = 0; ct < 4; ++ct) {
      const int tg = t0 + ct * 16 + l15;
      ui4 cv;
      #pragma unroll
      for (int m = 0; m < 4; ++m)
        cv[m] = (cp0 + m < 40) ? cpkB[(cp0 + m) * TF + tg] : 0u;
      s8v bh = __builtin_bit_cast(s8v, cv);
      accA[ct] = __builtin_amdgcn_mfma_f32_16x16x32_bf16(ah0, bh, accA[ct], 0, 0, 0);
      accG[ct] = __builtin_amdgcn_mfma_f32_16x16x32_bf16(ah1, bh, accG[ct], 0, 0, 0);
      accA[ct] = __builtin_amdgcn_mfma_f32_16x16x32_bf16(al0, bh, accA[ct], 0, 0, 0);
      accG[ct] = __builtin_amdgcn_mfma_f32_16x16x32_bf16(al1, bh, accG[ct], 0, 0, 0);
    }
  }

  float rres[16];
  #pragma unroll
  for (int ct = 0; ct < 4; ++ct) {
    const int t = ct * 16 + l15;
    uint2 rh = *(const uint2*)&Xhi[t][64 + r0e];
    uint2 rl = *(const uint2*)&Xlo[t][64 + r0e];
    rres[ct * 4 + 0] = us2f(rh.x & 0xffffu) + us2f(rl.x & 0xffffu);
    rres[ct * 4 + 1] = us2f(rh.x >> 16)     + us2f(rl.x >> 16);
    rres[ct * 4 + 2] = us2f(rh.y & 0xffffu) + us2f(rl.y & 0xffffu);
    rres[ct * 4 + 3] = us2f(rh.y >> 16)     + us2f(rl.y >> 16);
  }
  __syncthreads();

  #pragma unroll
  for (int ct = 0; ct < 4; ++ct) {
    const int t = ct * 16 + l15;
    unsigned int hw[2], lw[2];
    #pragma unroll
    for (int p = 0; p < 2; ++p) {
      float z0 = gatef(accA[ct][2 * p],     accG[ct][2 * p]);
      float z1 = gatef(accA[ct][2 * p + 1], accG[ct][2 * p + 1]);
      unsigned int h0 = f2b(z0), h1 = f2b(z1);
      hw[p] = h0 | (h1 << 16);
      lw[p] = (unsigned int)f2b(z0 - us2f(h0)) | ((unsigned int)f2b(z1 - us2f(h1)) << 16);
    }
    uint2 hv; hv.x = hw[0]; hv.y = hw[1];
    uint2 lv; lv.x = lw[0]; lv.y = lw[1];
    *(uint2*)&Zhi[t][r0e] = hv;
    *(uint2*)&Zlo[t][r0e] = lv;
  }
  __syncthreads();

  f4v accS[4], accH[4];
  {
    f4v bS = *(const f4v*)(sb + r0e);
    f4v bO = *(const f4v*)(ob + r0e);
    #pragma unroll
    for (int ct = 0; ct < 4; ++ct) { accS[ct] = bS; accH[ct] = bO; }
  }
  #pragma unroll
  for (int s = 0; s < 2; ++s) {
    const int k0 = s * 32 + ko;
    s8v ah0 = *(const s8v*)(w2h + (R0 + l15) * 64 + k0);
    s8v ah1 = *(const s8v*)(w2h + (R1 + l15) * 64 + k0);
    s8v al0 = *(const s8v*)(w2l + (R0 + l15) * 64 + k0);
    s8v al1 = *(const s8v*)(w2l + (R1 + l15) * 64 + k0);
    #pragma unroll
    for (int ct = 0; ct < 4; ++ct) {
      s8v bh = *(const s8v*)&Zhi[ct * 16 + l15][k0];
      s8v bl = *(const s8v*)&Zlo[ct * 16 + l15][k0];
      accS[ct] = __builtin_amdgcn_mfma_f32_16x16x32_bf16(ah0, bh, accS[ct], 0, 0, 0);
      accH[ct] = __builtin_amdgcn_mfma_f32_16x16x32_bf16(ah1, bh, accH[ct], 0, 0, 0);
      accS[ct] = __builtin_amdgcn_mfma_f32_16x16x32_bf16(al0, bh, accS[ct], 0, 0, 0);
      accH[ct] = __builtin_amdgcn_mfma_f32_16x16x32_bf16(al1, bh, accH[ct], 0, 0, 0);
      accS[ct] = __builtin_amdgcn_mfma_f32_16x16x32_bf16(ah0, bl, accS[ct], 0, 0, 0);
      accH[ct] = __builtin_amdgcn_mfma_f32_16x16x32_bf16(ah1, bl, accH[ct], 0, 0, 0);
    }
  }

  unsigned int* hho = hhi_out + ((size_t)b * 32 + (r0e >> 1)) * TF + t0;
  unsigned int* hlo = hlo_out + ((size_t)b * 32 + (r0e >> 1)) * TF + t0;
  #pragma unroll
  for (int ct = 0; ct < 4; ++ct) {
    const int t = ct * 16 + l15;
    sp_[0 * TF + t] = s_old[ct * 4 + 0] + accS[ct][0];
    sp_[1 * TF + t] = s_old[ct * 4 + 1] + accS[ct][1];
    sp_[2 * TF + t] = s_old[ct * 4 + 2] + accS[ct][2];
    sp_[3 * TF + t] = s_old[ct * 4 + 3] + accS[ct][3];
    if (!(mode & 2)) {
      float h0 = accH[ct][0] + rres[ct * 4 + 0];
      float h1 = accH[ct][1] + rres[ct * 4 + 1];
      float h2 = accH[ct][2] + rres[ct * 4 + 2];
      float h3 = accH[ct][3] + rres[ct * 4 + 3];
      unsigned int a0 = f2b(h0), a1 = f2b(h1), a2 = f2b(h2), a3 = f2b(h3);
      hho[t]      = a0 | (a1 << 16);
      hho[TF + t] = a2 | (a3 << 16);
      hlo[t]      = (unsigned int)f2b(h0 - us2f(a0)) | ((unsigned int)f2b(h1 - us2f(a1)) << 16);
      hlo[TF + t] = (unsigned int)f2b(h2 - us2f(a2)) | ((unsigned int)f2b(h3 - us2f(a3)) << 16);
    }
  }
}

// ---------- fused pair of layers (l, l+1): h1 stays in LDS, one skips RMW ----------
// ROWS = 64 + HALO; HALO multiple of 16, >= d2. Layer l computed over all ROWS
// (halo recompute), layer l+1 over owned 64 cols. Halo rows with global t<0 are
// zeroed at the h1 write (reference zero-padding semantics).
template<int ROWS>
__global__ __launch_bounds__(256, 3) void k_fused(
    const unsigned int* __restrict__ hhi_in, const unsigned int* __restrict__ hlo_in,
    unsigned int* __restrict__ hhi_out, unsigned int* __restrict__ hlo_out,
    float* __restrict__ skips, const unsigned int* __restrict__ cpk,
    const unsigned short* __restrict__ w1hA, const unsigned short* __restrict__ w1lA,
    const unsigned short* __restrict__ w2hA, const unsigned short* __restrict__ w2lA,
    const float* __restrict__ dbA, const float* __restrict__ sbA, const float* __restrict__ obA,
    const unsigned short* __restrict__ w1hB, const unsigned short* __restrict__ w1lB,
    const unsigned short* __restrict__ w2hB, const unsigned short* __restrict__ w2lB,
    const float* __restrict__ dbB, const float* __restrict__ sbB, const float* __restrict__ obB,
    int d1, int d2, int mode) {
  constexpr int HALO = ROWS - 64;
  constexpr int CT1 = ROWS / 16;
  constexpr int OG0 = HALO / 16;
  constexpr int TQ = ROWS / 4;
  // LDS map (bytes): X1 = [0, ROWS*512): XpvH/XpvL/XcH/XcL each ROWS*128.
  // After ph1+rres1: Z1H/Z1L at [0, ROWS*288); X2H/X2L at [ROWS*288, ROWS*544).
  // After ph2-l1: Z2H/Z2L at [0, 18432).
  __shared__ __align__(16) unsigned char smem[ROWS * 544];
  typedef unsigned short (*a64)[64];
  typedef unsigned short (*a72)[72];
  a64 XpvH = (a64)(smem);
  a64 XpvL = (a64)(smem + ROWS * 128);
  a64 XcH  = (a64)(smem + ROWS * 256);
  a64 XcL  = (a64)(smem + ROWS * 384);
  a72 Z1H  = (a72)(smem);
  a72 Z1L  = (a72)(smem + ROWS * 144);
  a64 X2H  = (a64)(smem + ROWS * 288);
  a64 X2L  = (a64)(smem + ROWS * 416);
  a72 Z2H  = (a72)(smem);
  a72 Z2L  = (a72)(smem + 9216);

  const int obid = (blockIdx.x & 7) * 250 + (blockIdx.x >> 3);
  const int b = obid / 500;
  const int t0 = (obid % 500) * 64;
  const int tb = t0 - HALO;                 // global t of LDS row 0
  const int tid = threadIdx.x;
  const int wv = tid >> 6, l15 = tid & 15, kl = (tid >> 4) & 3;
  const int R0 = wv * 16, R1 = 64 + wv * 16;
  const int ko = kl * 8;
  const unsigned int* hhiB = hhi_in + (size_t)b * 32 * TF;
  const unsigned int* hloB = hlo_in + (size_t)b * 32 * TF;
  const unsigned int* cpkB = cpk + (size_t)b * 40 * TF;

  // skips prefetch (owned cols only)
  const int r0e = R0 + kl * 4;
  float* sp_ = skips + ((size_t)b * 64 + r0e) * TF + t0;
  float s_old[16];
  if (!(mode & 1)) {
    #pragma unroll
    for (int og = 0; og < 4; ++og) {
      const int t = og * 16 + l15;
      s_old[og * 4 + 0] = sp_[0 * TF + t];
      s_old[og * 4 + 1] = sp_[1 * TF + t];
      s_old[og * 4 + 2] = sp_[2 * TF + t];
      s_old[og * 4 + 3] = sp_[3 * TF + t];
    }
  } else {
    #pragma unroll
    for (int q = 0; q < 16; ++q) s_old[q] = 0.f;
  }

  // ---- stage X1: hc = h_in[tb+r], hprev = h_in[tb+r-d1] over ROWS rows ----
  const bool d4 = (d1 & 3) == 0;
  for (int u = tid; u < 2 * 32 * TQ; u += 256) {
    const int tq = u % TQ;
    const int cp = (u / TQ) & 31;
    const int arr = u / (32 * TQ);          // 0 = hc, 1 = hprev
    const int rowg = cp * TF;
    const int base = tb + tq * 4 - (arr ? d1 : 0);
    ui4 hv, lv;
    if (base >= 0 && (arr == 0 || d4)) {
      hv = *(const ui4*)(hhiB + rowg + base);
      lv = *(const ui4*)(hloB + rowg + base);
    } else {
      #pragma unroll
      for (int q = 0; q < 4; ++q) {
        int tp = base + q;
        hv[q] = tp >= 0 ? hhiB[rowg + tp] : 0u;
        lv[q] = tp >= 0 ? hloB[rowg + tp] : 0u;
      }
    }
    const int colb = cp * 2;
    if (arr == 0) {
      #pragma unroll
      for (int q = 0; q < 4; ++q) {
        *(unsigned int*)&XcH[tq * 4 + q][colb] = hv[q];
        *(unsigned int*)&XcL[tq * 4 + q][colb] = lv[q];
      }
    } else {
      #pragma unroll
      for (int q = 0; q < 4; ++q) {
        *(unsigned int*)&XpvH[tq * 4 + q][colb] = hv[q];
        *(unsigned int*)&XpvL[tq * 4 + q][colb] = lv[q];
      }
    }
  }
  __syncthreads();   // (1)

  // ---- ph1 of layer l over all ROWS ----
  f4v accA[CT1], accG[CT1];
  {
    f4v bA = *(const f4v*)(dbA + r0e);
    f4v bG = *(const f4v*)(dbA + R1 + kl * 4);
    #pragma unroll
    for (int g = 0; g < CT1; ++g) { accA[g] = bA; accG[g] = bG; }
  }
  #pragma unroll
  for (int s = 0; s < 4; ++s) {
    const int k0 = s * 32 + ko;
    s8v ah0 = *(const s8v*)(w1hA + (R0 + l15) * 224 + k0);
    s8v ah1 = *(const s8v*)(w1hA + (R1 + l15) * 224 + k0);
    s8v al0 = *(const s8v*)(w1lA + (R0 + l15) * 224 + k0);
    s8v al1 = *(const s8v*)(w1lA + (R1 + l15) * 224 + k0);
    #pragma unroll
    for (int g = 0; g < CT1; ++g) {
      const int r = g * 16 + l15;
      s8v bh, bl;
      if (s < 2) { bh = *(const s8v*)&XpvH[r][k0];      bl = *(const s8v*)&XpvL[r][k0]; }
      else       { bh = *(const s8v*)&XcH[r][k0 - 64];  bl = *(const s8v*)&XcL[r][k0 - 64]; }
      accA[g] = __builtin_amdgcn_mfma_f32_16x16x32_bf16(ah0, bh, accA[g], 0, 0, 0);
      accG[g] = __builtin_amdgcn_mfma_f32_16x16x32_bf16(ah1, bh, accG[g], 0, 0, 0);
      accA[g] = __builtin_amdgcn_mfma_f32_16x16x32_bf16(al0, bh, accA[g], 0, 0, 0);
      accG[g] = __builtin_amdgcn_mfma_f32_16x16x32_bf16(al1, bh, accG[g], 0, 0, 0);
      accA[g] = __builtin_amdgcn_mfma_f32_16x16x32_bf16(ah0, bl, accA[g], 0, 0, 0);
      accG[g] = __builtin_amdgcn_mfma_f32_16x16x32_bf16(ah1, bl, accG[g], 0, 0, 0);
    }
  }
  #pragma unroll
  for (int s = 4; s < 7; ++s) {
    const int k0 = s * 32 + ko;
    s8v ah0 = *(const s8v*)(w1hA + (R0 + l15) * 224 + k0);
    s8v ah1 = *(const s8v*)(w1hA + (R1 + l15) * 224 + k0);
    s8v al0 = *(const s8v*)(w1lA + (R0 + l15) * 224 + k0);
    s8v al1 = *(const s8v*)(w1lA + (R1 + l15) * 224 + k0);
    const int cp0 = (k0 - 128) >> 1;
    #pragma unroll
    for (int g = 0; g < CT1; ++g) {
      const int tg = tb + g * 16 + l15;
      ui4 cv;
      #pragma unroll
      for (int m = 0; m < 4; ++m)
        cv[m] = (tg >= 0 && cp0 + m < 40) ? cpkB[(cp0 + m) * TF + tg] : 0u;
      s8v bh = __builtin_bit_cast(s8v, cv);
      accA[g] = __builtin_amdgcn_mfma_f32_16x16x32_bf16(ah0, bh, accA[g], 0, 0, 0);
      accG[g] = __builtin_amdgcn_mfma_f32_16x16x32_bf16(ah1, bh, accG[g], 0, 0, 0);
      accA[g] = __builtin_amdgcn_mfma_f32_16x16x32_bf16(al0, bh, accA[g], 0, 0, 0);
      accG[g] = __builtin_amdgcn_mfma_f32_16x16x32_bf16(al1, bh, accG[g], 0, 0, 0);
    }
  }

  // ---- residual hc of layer l -> regs (X dead after this) ----
  float rres1[CT1 * 4];
  #pragma unroll
  for (int g = 0; g < CT1; ++g) {
    const int r = g * 16 + l15;
    uint2 rh = *(const uint2*)&XcH[r][r0e];
    uint2 rl = *(const uint2*)&XcL[r][r0e];
    rres1[g * 4 + 0] = us2f(rh.x & 0xffffu) + us2f(rl.x & 0xffffu);
    rres1[g * 4 + 1] = us2f(rh.x >> 16)     + us2f(rl.x >> 16);
    rres1[g * 4 + 2] = us2f(rh.y & 0xffffu) + us2f(rl.y & 0xffffu);
    rres1[g * 4 + 3] = us2f(rh.y >> 16)     + us2f(rl.y >> 16);
  }
  __syncthreads();   // (2)

  // ---- gate1 -> Z1 (aliases X) ----
  #pragma unroll
  for (int g = 0; g < CT1; ++g) {
    const int r = g * 16 + l15;
    unsigned int hw[2], lw[2];
    #pragma unroll
    for (int p = 0; p < 2; ++p) {
      float z0 = gatef(accA[g][2 * p],     accG[g][2 * p]);
      float z1 = gatef(accA[g][2 * p + 1], accG[g][2 * p + 1]);
      unsigned int h0 = f2b(z0), h1 = f2b(z1);
      hw[p] = h0 | (h1 << 16);
      lw[p] = (unsigned int)f2b(z0 - us2f(h0)) | ((unsigned int)f2b(z1 - us2f(h1)) << 16);
    }
    uint2 hv; hv.x = hw[0]; hv.y = hw[1];
    uint2 lv; lv.x = lw[0]; lv.y = lw[1];
    *(uint2*)&Z1H[r][r0e] = hv;
    *(uint2*)&Z1L[r][r0e] = lv;
  }
  __syncthreads();   // (3)

  // ---- ph2 of layer l: S1 (kept for owned groups), h1 -> X2 ----
  f4v accS1[CT1], accH1[CT1];
  {
    f4v bS = *(const f4v*)(sbA + r0e);
    f4v bO = *(const f4v*)(obA + r0e);
    #pragma unroll
    for (int g = 0; g < CT1; ++g) { accS1[g] = bS; accH1[g] = bO; }
  }
  #pragma unroll
  for (int s = 0; s < 2; ++s) {
    const int k0 = s * 32 + ko;
    s8v ah0 = *(const s8v*)(w2hA + (R0 + l15) * 64 + k0);
    s8v ah1 = *(const s8v*)(w2hA + (R1 + l15) * 64 + k0);
    s8v al0 = *(const s8v*)(w2lA + (R0 + l15) * 64 + k0);
    s8v al1 = *(const s8v*)(w2lA + (R1 + l15) * 64 + k0);
    #pragma unroll
    for (int g = 0; g < CT1; ++g) {
      s8v bh = *(const s8v*)&Z1H[g * 16 + l15][k0];
      s8v bl = *(const s8v*)&Z1L[g * 16 + l15][k0];
      accS1[g] = __builtin_amdgcn_mfma_f32_16x16x32_bf16(ah0, bh, accS1[g], 0, 0, 0);
      accH1[g] = __builtin_amdgcn_mfma_f32_16x16x32_bf16(ah1, bh, accH1[g], 0, 0, 0);
      accS1[g] = __builtin_amdgcn_mfma_f32_16x16x32_bf16(al0, bh, accS1[g], 0, 0, 0);
      accH1[g] = __builtin_amdgcn_mfma_f32_16x16x32_bf16(al1, bh, accH1[g], 0, 0, 0);
      accS1[g] = __builtin_amdgcn_mfma_f32_16x16x32_bf16(ah0, bl, accS1[g], 0, 0, 0);
      accH1[g] = __builtin_amdgcn_mfma_f32_16x16x32_bf16(ah1, bl, accH1[g], 0, 0, 0);
    }
  }
  // h1 = H + rres1 (zero where global t < 0) -> X2 split
  #pragma unroll
  for (int g = 0; g < CT1; ++g) {
    const int r = g * 16 + l15;
    const int tg = tb + r;
    float h0 = accH1[g][0] + rres1[g * 4 + 0];
    float h1 = accH1[g][1] + rres1[g * 4 + 1];
    float h2 = accH1[g][2] + rres1[g * 4 + 2];
    float h3 = accH1[g][3] + rres1[g * 4 + 3];
    if (tg < 0) { h0 = 0.f; h1 = 0.f; h2 = 0.f; h3 = 0.f; }
    unsigned int a0 = f2b(h0), a1 = f2b(h1), a2 = f2b(h2), a3 = f2b(h3);
    uint2 hv, lv;
    hv.x = a0 | (a1 << 16);
    hv.y = a2 | (a3 << 16);
    lv.x = (unsigned int)f2b(h0 - us2f(a0)) | ((unsigned int)f2b(h1 - us2f(a1)) << 16);
    lv.y = (unsigned int)f2b(h2 - us2f(a2)) | ((unsigned int)f2b(h3 - us2f(a3)) << 16);
    *(uint2*)&X2H[r][r0e] = hv;
    *(uint2*)&X2L[r][r0e] = lv;
  }
  f4v sOwn[4];
  #pragma unroll
  for (int og = 0; og < 4; ++og) sOwn[og] = accS1[og + OG0];
  __syncthreads();   // (4)

  // ---- ph1 of layer l+1 over owned 64 cols (h from X2; hprev = X2 shifted) ----
  f4v accA2[4], accG2[4];
  {
    f4v bA = *(const f4v*)(dbB + r0e);
    f4v bG = *(const f4v*)(dbB + R1 + kl * 4);
    #pragma unroll
    for (int og = 0; og < 4; ++og) { accA2[og] = bA; accG2[og] = bG; }
  }
  #pragma unroll
  for (int s = 0; s < 4; ++s) {
    const int k0 = s * 32 + ko;
    s8v ah0 = *(const s8v*)(w1hB + (R0 + l15) * 224 + k0);
    s8v ah1 = *(const s8v*)(w1hB + (R1 + l15) * 224 + k0);
    s8v al0 = *(const s8v*)(w1lB + (R0 + l15) * 224 + k0);
    s8v al1 = *(const s8v*)(w1lB + (R1 + l15) * 224 + k0);
    #pragma unroll
    for (int og = 0; og < 4; ++og) {
      const int r = HALO + og * 16 + l15;
      s8v bh, bl;
      if (s < 2) { bh = *(const s8v*)&X2H[r - d2][k0];     bl = *(const s8v*)&X2L[r - d2][k0]; }
      else       { bh = *(const s8v*)&X2H[r][k0 - 64];     bl = *(const s8v*)&X2L[r][k0 - 64]; }
      accA2[og] = __builtin_amdgcn_mfma_f32_16x16x32_bf16(ah0, bh, accA2[og], 0, 0, 0);
      accG2[og] = __builtin_amdgcn_mfma_f32_16x16x32_bf16(ah1, bh, accG2[og], 0, 0, 0);
      accA2[og] = __builtin_amdgcn_mfma_f32_16x16x32_bf16(al0, bh, accA2[og], 0, 0, 0);
      accG2[og] = __builtin_amdgcn_mfma_f32_16x16x32_bf16(al1, bh, accG2[og], 0, 0, 0);
      accA2[og] = __builtin_amdgcn_mfma_f32_16x16x32_bf16(ah0, bl, accA2[og], 0, 0, 0);
      accG2[og] = __builtin_amdgcn_mfma_f32_16x16x32_bf16(ah1, bl, accG2[og], 0, 0, 0);
    }
  }
  #pragma unroll
  for (int s = 4; s < 7; ++s) {
    const int k0 = s * 32 + ko;
    s8v ah0 = *(const s8v*)(w1hB + (R0 + l15) * 224 + k0);
    s8v ah1 = *(const s8v*)(w1hB + (R1 + l15) * 224 + k0);
    s8v al0 = *(const s8v*)(w1lB + (R0 + l15) * 224 + k0);
    s8v al1 = *(const s8v*)(w1lB + (R1 + l15) * 224 + k0);
    const int cp0 = (k0 - 128) >> 1;
    #pragma unroll
    for (int og = 0; og < 4; ++og) {
      const int tg = t0 + og * 16 + l15;
      ui4 cv;
      #pragma unroll
      for (int m = 0; m < 4; ++m)
        cv[m] = (cp0 + m < 40) ? cpkB[(cp0 + m) * TF + tg] : 0u;
      s8v bh = __builtin_bit_cast(s8v, cv);
      accA2[og] = __builtin_amdgcn_mfma_f32_16x16x32_bf16(ah0, bh, accA2[og], 0, 0, 0);
      accG2[og] = __builtin_amdgcn_mfma_f32_16x16x32_bf16(ah1, bh, accG2[og], 0, 0, 0);
      accA2[og] = __builtin_amdgcn_mfma_f32_16x16x32_bf16(al0, bh, accA2[og], 0, 0, 0);
      accG2[og] = __builtin_amdgcn_mfma_f32_16x16x32_bf16(al1, bh, accG2[og], 0, 0, 0);
    }
  }

  // ---- residual h1 (owned rows) from X2 ----
  float rres2[16];
  #pragma unroll
  for (int og = 0; og < 4; ++og) {
    const int r = HALO + og * 16 + l15;
    uint2 rh = *(const uint2*)&X2H[r][r0e];
    uint2 rl = *(const uint2*)&X2L[r][r0e];
    rres2[og * 4 + 0] = us2f(rh.x & 0xffffu) + us2f(rl.x & 0xffffu);
    rres2[og * 4 + 1] = us2f(rh.x >> 16)     + us2f(rl.x >> 16);
    rres2[og * 4 + 2] = us2f(rh.y & 0xffffu) + us2f(rl.y & 0xffffu);
    rres2[og * 4 + 3] = us2f(rh.y >> 16)     + us2f(rl.y >> 16);
  }

  // ---- gate2 -> Z2 (aliases Z1; Z1 dead after sync 4) ----
  #pragma unroll
  for (int og = 0; og < 4; ++og) {
    const int r = og * 16 + l15;
    unsigned int hw[2], lw[2];
    #pragma unroll
    for (int p = 0; p < 2; ++p) {
      float z0 = gatef(accA2[og][2 * p],     accG2[og][2 * p]);
      float z1 = gatef(accA2[og][2 * p + 1], accG2[og][2 * p + 1]);
      unsigned int h0 = f2b(z0), h1 = f2b(z1);
      hw[p] = h0 | (h1 << 16);
      lw[p] = (unsigned int)f2b(z0 - us2f(h0)) | ((unsigned int)f2b(z1 - us2f(h1)) << 16);
    }
    uint2 hv; hv.x = hw[0]; hv.y = hw[1];
    uint2 lv; lv.x = lw[0]; lv.y = lw[1];
    *(uint2*)&Z2H[r][r0e] = hv;
    *(uint2*)&Z2L[r][r0e] = lv;
  }
  __syncthreads();   // (5)

  // ---- ph2 of layer l+1 ----
  f4v accS2[4], accH2[4];
  {
    f4v bS = *(const f4v*)(sbB + r0e);
    f4v bO = *(const f4v*)(obB + r0e);
    #pragma unroll
    for (int og = 0; og < 4; ++og) { accS2[og] = bS; accH2[og] = bO; }
  }
  #pragma unroll
  for (int s = 0; s < 2; ++s) {
    const int k0 = s * 32 + ko;
    s8v ah0 = *(const s8v*)(w2hB + (R0 + l15) * 64 + k0);
    s8v ah1 = *(const s8v*)(w2hB + (R1 + l15) * 64 + k0);
    s8v al0 = *(const s8v*)(w2lB + (R0 + l15) * 64 + k0);
    s8v al1 = *(const s8v*)(w2lB + (R1 + l15) * 64 + k0);
    #pragma unroll
    for (int og = 0; og < 4; ++og) {
      s8v bh = *(const s8v*)&Z2H[og * 16 + l15][k0];
      s8v bl = *(const s8v*)&Z2L[og * 16 + l15][k0];
      accS2[og] = __builtin_amdgcn_mfma_f32_16x16x32_bf16(ah0, bh, accS2[og], 0, 0, 0);
      accH2[og] = __builtin_amdgcn_mfma_f32_16x16x32_bf16(ah1, bh, accH2[og], 0, 0, 0);
      accS2[og] = __builtin_amdgcn_mfma_f32_16x16x32_bf16(al0, bh, accS2[og], 0, 0, 0);
      accH2[og] = __builtin_amdgcn_mfma_f32_16x16x32_bf16(al1, bh, accH2[og], 0, 0, 0);
      accS2[og] = __builtin_amdgcn_mfma_f32_16x16x32_bf16(ah0, bl, accS2[og], 0, 0, 0);
      accH2[og] = __builtin_amdgcn_mfma_f32_16x16x32_bf16(ah1, bl, accH2[og], 0, 0, 0);
    }
  }

  // ---- epilogue: one skips RMW for both layers; h_out = h2 ----
  unsigned int* hho = hhi_out + ((size_t)b * 32 + (r0e >> 1)) * TF + t0;
  unsigned int* hlo = hlo_out + ((size_t)b * 32 + (r0e >> 1)) * TF + t0;
  #pragma unroll
  for (int og = 0; og < 4; ++og) {
    const int t = og * 16 + l15;
    sp_[0 * TF + t] = s_old[og * 4 + 0] + sOwn[og][0] + accS2[og][0];
    sp_[1 * TF + t] = s_old[og * 4 + 1] + sOwn[og][1] + accS2[og][1];
    sp_[2 * TF + t] = s_old[og * 4 + 2] + sOwn[og][2] + accS2[og][2];
    sp_[3 * TF + t] = s_old[og * 4 + 3] + sOwn[og][3] + accS2[og][3];
    float h0 = accH2[og][0] + rres2[og * 4 + 0];
    float h1 = accH2[og][1] + rres2[og * 4 + 1];
    float h2 = accH2[og][2] + rres2[og * 4 + 2];
    float h3 = accH2[og][3] + rres2[og * 4 + 3];
    unsigned int a0 = f2b(h0), a1 = f2b(h1), a2 = f2b(h2), a3 = f2b(h3);
    hho[t]      = a0 | (a1 << 16);
    hho[TF + t] = a2 | (a3 << 16);
    hlo[t]      = (unsigned int)f2b(h0 - us2f(a0)) | ((unsigned int)f2b(h1 - us2f(a1)) << 16);
    hlo[TF + t] = (unsigned int)f2b(h2 - us2f(a2)) | ((unsigned int)f2b(h3 - us2f(a3)) << 16);
  }
}

// ---------- final head: MFMA split-bf16 ----------
__global__ __launch_bounds__(256, 4) void k_final(
    const float* __restrict__ skips,
    const float* __restrict__ w1, const float* __restrict__ b1,
    const float* __restrict__ w2, const float* __restrict__ b2,
    float* __restrict__ out) {
  __shared__ __align__(16) unsigned short Shi[64][72];
  __shared__ __align__(16) unsigned short Slo[64][72];
  __shared__ __align__(16) unsigned short Zhi[64][72];
  __shared__ __align__(16) unsigned short Zlo[64][72];
  const int obid = (blockIdx.x & 7) * 250 + (blockIdx.x >> 3);
  const int b = obid / 500;
  const int t0 = (obid % 500) * 64;
  const int tid = threadIdx.x;
  const float* sbase = skips + (size_t)b * 64 * TF;

  for (int u = tid; u < 512; u += 256) {
    const int cp = u >> 4, tq = u & 15, ch0 = cp * 2;
    float4 A = *(const float4*)(sbase + (size_t)ch0 * TF + t0 + tq * 4);
    float4 B = *(const float4*)(sbase + (size_t)(ch0 + 1) * TF + t0 + tq * 4);
    float va[4] = {fmaxf(A.x, 0.f), fmaxf(A.y, 0.f), fmaxf(A.z, 0.f), fmaxf(A.w, 0.f)};
    float vb[4] = {fmaxf(B.x, 0.f), fmaxf(B.y, 0.f), fmaxf(B.z, 0.f), fmaxf(B.w, 0.f)};
    #pragma unroll
    for (int j = 0; j < 4; ++j) {
      int t = tq * 4 + j;
      unsigned int h0 = f2b(va[j]), h1 = f2b(vb[j]);
      *(unsigned int*)&Shi[t][ch0] = h0 | (h1 << 16);
      *(unsigned int*)&Slo[t][ch0] =
          (unsigned int)f2b(va[j] - us2f(h0)) | ((unsigned int)f2b(vb[j] - us2f(h1)) << 16);
    }
  }
  __syncthreads();

  const int wv = tid >> 6, l15 = tid & 15, kl = (tid >> 4) & 3;
  const int R = wv * 16;

  f4v acc[4];
  {
    f4v bb = *(const f4v*)(b1 + R + kl * 4);
    #pragma unroll
    for (int ct = 0; ct < 4; ++ct) acc[ct] = bb;
  }
  #pragma unroll
  for (int ks = 0; ks < 2; ++ks) {
    const int k0 = ks * 32 + kl * 8;
    const float* wr = w1 + (R + l15) * 64 + k0;
    s8v ah, al;
    #pragma unroll
    for (int m = 0; m < 8; ++m) {
      float v = wr[m];
      unsigned short hh = f2b(v);
      ah[m] = (short)hh;
      al[m] = (short)f2b(v - us2f(hh));
    }
    #pragma unroll
    for (int ct = 0; ct < 4; ++ct) {
      s8v bh = *(const s8v*)&Shi[ct * 16 + l15][k0];
      s8v bl = *(const s8v*)&Slo[ct * 16 + l15][k0];
      acc[ct] = __builtin_amdgcn_mfma_f32_16x16x32_bf16(ah, bh, acc[ct], 0, 0, 0);
      acc[ct] = __builtin_amdgcn_mfma_f32_16x16x32_bf16(al, bh, acc[ct], 0, 0, 0);
      acc[ct] = __builtin_amdgcn_mfma_f32_16x16x32_bf16(ah, bl, acc[ct], 0, 0, 0);
    }
  }
  #pragma unroll
  for (int ct = 0; ct < 4; ++ct) {
    const int t = ct * 16 + l15;
    unsigned int hw[2], lw[2];
    #pragma unroll
    for (int p = 0; p < 2; ++p) {
      float z0 = fmaxf(acc[ct][2 * p], 0.f);
      float z1 = fmaxf(acc[ct][2 * p + 1], 0.f);
      unsigned int h0 = f2b(z0), h1 = f2b(z1);
      hw[p] = h0 | (h1 << 16);
      lw[p] = (unsigned int)f2b(z0 - us2f(h0)) | ((unsigned int)f2b(z1 - us2f(h1)) << 16);
    }
    uint2 hv; hv.x = hw[0]; hv.y = hw[1];
    uint2 lv; lv.x = lw[0]; lv.y = lw[1];
    *(uint2*)&Zhi[t][R + kl * 4] = hv;
    *(uint2*)&Zlo[t][R + kl * 4] = lv;
  }
  __syncthreads();

  float* obase = out + (size_t)b * 256 * TF + t0;
  #pragma unroll
  for (int g = 0; g < 4; ++g) {
    const int R2 = g * 64 + wv * 16;
    f4v a2[4];
    {
      f4v bb = *(const f4v*)(b2 + R2 + kl * 4);
      #pragma unroll
      for (int ct = 0; ct < 4; ++ct) a2[ct] = bb;
    }
    #pragma unroll
    for (int ks = 0; ks < 2; ++ks) {
      const int k0 = ks * 32 + kl * 8;
      const float* wr = w2 + (R2 + l15) * 64 + k0;
      s8v ah, al;
      #pragma unroll
      for (int m = 0; m < 8; ++m) {
        float v = wr[m];
        unsigned short hh = f2b(v);
        ah[m] = (short)hh;
        al[m] = (short)f2b(v - us2f(hh));
      }
      #pragma unroll
      for (int ct = 0; ct < 4; ++ct) {
        s8v bh = *(const s8v*)&Zhi[ct * 16 + l15][k0];
        s8v bl = *(const s8v*)&Zlo[ct * 16 + l15][k0];
        a2[ct] = __builtin_amdgcn_mfma_f32_16x16x32_bf16(ah, bh, a2[ct], 0, 0, 0);
        a2[ct] = __builtin_amdgcn_mfma_f32_16x16x32_bf16(al, bh, a2[ct], 0, 0, 0);
        a2[ct] = __builtin_amdgcn_mfma_f32_16x16x32_bf16(ah, bl, a2[ct], 0, 0, 0);
      }
    }
    const int r0 = R2 + kl * 4;
    #pragma unroll
    for (int ct = 0; ct < 4; ++ct) {
      const int t = ct * 16 + l15;
      obase[(size_t)(r0 + 0) * TF + t] = a2[ct][0];
      obase[(size_t)(r0 + 1) * TF + t] = a2[ct][1];
      obase[(size_t)(r0 + 2) * TF + t] = a2[ct][2];
      obase[(size_t)(r0 + 3) * TF + t] = a2[ct][3];
    }
  }
}

extern "C" void kernel_launch(void* const* d_in, const int* in_sizes, int n_in,
                              void* d_out, int out_size, void* d_ws, size_t ws_size,
                              hipStream_t stream) {
  const int* x = (const int*)d_in[0];

  float* ws = (float*)d_ws;
  int*   flag = (int*)ws;
  float* wcan = ws + 16;
  unsigned int* cpkb = (unsigned int*)(ws + 1095872);
  float* ha    = ws + 6215872;
  float* hbuf  = ws + 14407872;
  float* skips = ws + 22599872;
  float* cin = ha;
  float* c0  = ha + 128000;
  float* s1f = ha + 256000;
  if (ws_size < (size_t)30791872 * 4) return;

  unsigned int* haHi = (unsigned int*)ha;
  unsigned int* haLo = haHi + 4096000;
  unsigned int* hbHi = (unsigned int*)hbuf;
  unsigned int* hbLo = hbHi + 4096000;

  float* fwc = wcan;            float* fbc = wcan + 16384;
  float* dbc = wcan + 507968;
  float* sbc = wcan + 941888;
  float* obc = wcan + 1066688;  float* w1c = wcan + 1068608;
  float* b1c = wcan + 1072704;  float* w2c = wcan + 1072768;
  float* b2c = wcan + 1089152;  float* ciwc = wcan + 1089408;
  float* uw0c = wcan + 1095808; float* uw1c = wcan + 1095829;

  unsigned short* wp = (unsigned short*)d_out;
  unsigned short* W1H = wp;
  unsigned short* W1L = wp + 860160;
  unsigned short* W2H = wp + 1720320;
  unsigned short* W2L = wp + 1966080;

  hipMemsetAsync(flag, 0, 64, stream);
  k_probe_x<<<dim3(32), dim3(256), 0, stream>>>(x, flag);
  k_probe_dt<<<dim3(64), dim3(256), 0, stream>>>((const unsigned short*)d_in[2], flag);

  SrcPtrs sp;
  sp.p[0] = d_in[2];  sp.p[1] = d_in[3];  sp.p[2] = d_in[4];  sp.p[3] = d_in[5];
  sp.p[4] = d_in[6];  sp.p[5] = d_in[7];  sp.p[6] = d_in[8];  sp.p[7] = d_in[9];
  sp.p[8] = d_in[10]; sp.p[9] = d_in[11]; sp.p[10] = d_in[12]; sp.p[11] = d_in[13];
  sp.p[12] = d_in[14]; sp.p[13] = d_in[15]; sp.p[14] = d_in[16]; sp.p[15] = d_in[17];
  sp.p[16] = d_in[1];
  k_cvt<<<dim3(4781), dim3(256), 0, stream>>>(sp, flag, wcan, cin);
  k_pack<<<dim3(4320), dim3(256), 0, stream>>>(wcan, W1H, W1L, W2H, W2L);

  k_convin<<<dim3(1600), dim3(128), 0, stream>>>(cin, ciwc, c0);
  k_up1<<<dim3(5000), dim3(256), 0, stream>>>(c0, uw0c, s1f);
  k_up2<<<dim3(20000), dim3(256), 0, stream>>>(s1f, uw1c, cpkb);
  k_first<<<dim3(16000), dim3(256), 0, stream>>>(x, flag, fwc, fbc, haHi, haLo);

  unsigned int* hiIn = haHi; unsigned int* loIn = haLo;
  unsigned int* hiOut = hbHi; unsigned int* loOut = hbLo;
  for (int l = 0; l < 30; ) {
    int m10 = l % 10;
    if (m10 == 0 || m10 == 2 || m10 == 4) {
      // fused pair (l, l+1): d2 = 2,8,32 -> ROWS = 80,80,96
      int d1 = 1 << m10, d2 = 1 << (m10 + 1);
      auto kern = (m10 == 4) ? &k_fused<96> : &k_fused<80>;
      kern<<<dim3(2000), dim3(256), 0, stream>>>(
          hiIn, loIn, hiOut, loOut, skips, cpkb,
          W1H + (size_t)l * 28672, W1L + (size_t)l * 28672,
          W2H + (size_t)l * 8192,  W2L + (size_t)l * 8192,
          dbc + l * 128, sbc + l * 64, obc + l * 64,
          W1H + (size_t)(l + 1) * 28672, W1L + (size_t)(l + 1) * 28672,
          W2H + (size_t)(l + 1) * 8192,  W2L + (size_t)(l + 1) * 8192,
          dbc + (l + 1) * 128, sbc + (l + 1) * 64, obc + (l + 1) * 64,
          d1, d2, (l == 0 ? 1 : 0));
      unsigned int* t;
      t = hiIn; hiIn = hiOut; hiOut = t;
      t = loIn; loIn = loOut; loOut = t;
      l += 2;
    } else {
      int d = 1 << m10;
      int mode = (l == 29 ? 2 : 0);
      k_layer<<<dim3(2000), dim3(256), 0, stream>>>(
          hiIn, loIn, hiOut, loOut, skips, cpkb,
          W1H + (size_t)l * 28672, W1L + (size_t)l * 28672,
          W2H + (size_t)l * 8192,  W2L + (size_t)l * 8192,
          dbc + l * 128, sbc + l * 64, obc + l * 64, d, mode);
      unsigned int* t;
      t = hiIn; hiIn = hiOut; hiOut = t;
      t = loIn; loIn = loOut; loOut = t;
      l += 1;
    }
  }
  k_final<<<dim3(2000), dim3(256), 0, stream>>>(skips, w1c, b1c, w2c, b2c,
                                                (float*)d_out);
}